// Round 10
// baseline (3339.680 us; speedup 1.0000x reference)
//
#include <hip/hip_runtime.h>

#define NJ  21
#define FT  6
#define TRS 43   // output tile row stride (floats); odd -> bank-conflict-free
#define WRS 12   // weight row stride: 10 w + bias@[10] + pad (48B, 16B-aligned)

// E=2 elements per thread (block covers 512 elements). The wall (r2-r7) is
// per-element weight-broadcast cost on the per-CU LDS pipe (~64 ds-instr/
// joint-set/wave, 16 waves sharing one pipe -> ~30% VALU ceiling).
// Levers here: (1) E=2 -> each weight ds_read feeds two element chains (CSE);
// (2) bias packed at row[10] -> rides the row's 3rd ds_read_b128 for free.
// r8/r9 lesson: __launch_bounds__ pins the RA to 8 waves/EU (VGPR=64) and it
// spills 22KB/thread rather than exceed it; amdgpu_waves_per_eu is IGNORED
// next to launch_bounds. So: NO launch_bounds; flat_work_group_size +
// waves_per_eu(4,4) alone -> 128-VGPR budget matching the LDS cap (4 blk/CU).

// relu(dot10 + bias), bias stored at (W)[10]
#define F10B(W, a0,a1,a2,a3,a4,a5,a6,a7,a8,a9) \
  fmaxf(fmaf((W)[9],(a9),fmaf((W)[8],(a8),fmaf((W)[7],(a7),fmaf((W)[6],(a6), \
        fmaf((W)[5],(a5),fmaf((W)[4],(a4),fmaf((W)[3],(a3),fmaf((W)[2],(a2), \
        fmaf((W)[1],(a1),fmaf((W)[0],(a0),(W)[10])))))))))), 0.0f)

#define HROW2(N,P,j,r) \
  const float hA##N##_##r = F10B(w1s + (((j)-1)*10 + (r))*WRS, \
      qA##N.x, qA##N.y, qA##N.z, qA##N.w, \
      fA##P##_0, fA##P##_1, fA##P##_2, fA##P##_3, fA##P##_4, fA##P##_5); \
  const float hB##N##_##r = F10B(w1s + (((j)-1)*10 + (r))*WRS, \
      qB##N.x, qB##N.y, qB##N.z, qB##N.w, \
      fB##P##_0, fB##P##_1, fB##P##_2, fB##P##_3, fB##P##_4, fB##P##_5);

#define FROW2(N,j,r) \
  const float fA##N##_##r = F10B(w2s + ((j)*6 + (r))*WRS, \
      hA##N##_0, hA##N##_1, hA##N##_2, hA##N##_3, hA##N##_4, \
      hA##N##_5, hA##N##_6, hA##N##_7, hA##N##_8, hA##N##_9); \
  const float fB##N##_##r = F10B(w2s + ((j)*6 + (r))*WRS, \
      hB##N##_0, hB##N##_1, hB##N##_2, hB##N##_3, hB##N##_4, \
      hB##N##_5, hB##N##_6, hB##N##_7, hB##N##_8, hB##N##_9);

#define DO_JOINT(j,P,N) \
  const float4 qA##N = qvA[j]; \
  const float4 qB##N = qvB[j]; \
  HROW2(N,P,j,0) HROW2(N,P,j,1) HROW2(N,P,j,2) HROW2(N,P,j,3) HROW2(N,P,j,4) \
  HROW2(N,P,j,5) HROW2(N,P,j,6) HROW2(N,P,j,7) HROW2(N,P,j,8) HROW2(N,P,j,9) \
  FROW2(N,j,0) FROW2(N,j,1) FROW2(N,j,2) FROW2(N,j,3) FROW2(N,j,4) FROW2(N,j,5)

#define PUT6(p, X) { (p)[0]=f##X##_0; (p)[1]=f##X##_1; (p)[2]=f##X##_2; \
                     (p)[3]=f##X##_3; (p)[4]=f##X##_4; (p)[5]=f##X##_5; }

// Quarter flush: quarter q covers block rows [q*128,(q+1)*128).
// q=0,1: element set A (threads 0-127 / 128-255); q=2,3: element set B.
#define QFLUSH(k, q, EL, N0,N1,N2,N3,N4,N5,N6) \
  __syncthreads(); \
  if ((tid >> 7) == ((q) & 1)) { \
    float* tr_ = tile + (tid & 127) * TRS; \
    PUT6(tr_+0,  EL##N0) PUT6(tr_+6,  EL##N1) PUT6(tr_+12, EL##N2) \
    PUT6(tr_+18, EL##N3) PUT6(tr_+24, EL##N4) PUT6(tr_+30, EL##N5) \
    PUT6(tr_+36, EL##N6) \
  } \
  __syncthreads(); \
  { const int lane_ = tid & 63, w_ = tid >> 6; \
    _Pragma("unroll") \
    for (int i_ = 0; i_ < 21; ++i_) { \
      const int idx_ = w_ * 1344 + i_ * 64 + lane_; \
      const int row_ = idx_ / 42, col_ = idx_ - row_ * 42; \
      const int rg_  = base + (q)*128 + row_; \
      if (rg_ < B) out[(size_t)rg_ * 126 + (k)*42 + col_] = tile[row_ * TRS + col_]; \
    } \
  }

#define CHUNK_FLUSH(k, N0,N1,N2,N3,N4,N5,N6) \
  QFLUSH(k, 0, A, N0,N1,N2,N3,N4,N5,N6) \
  QFLUSH(k, 1, A, N0,N1,N2,N3,N4,N5,N6) \
  QFLUSH(k, 2, B, N0,N1,N2,N3,N4,N5,N6) \
  QFLUSH(k, 3, B, N0,N1,N2,N3,N4,N5,N6)

__global__
__attribute__((amdgpu_flat_work_group_size(256, 256), amdgpu_waves_per_eu(4, 4)))
void se_kernel(
    const float* __restrict__ quat,   // [B, 21, 4]
    const float* __restrict__ W1r,    // [10, 4]
    const float* __restrict__ b1r,    // [10]
    const float* __restrict__ W1,     // [20, 10, 10]
    const float* __restrict__ b1,     // [20, 10]
    const float* __restrict__ W2,     // [21, 6, 10]
    const float* __restrict__ b2,     // [21, 6]
    float*       __restrict__ out,    // [B, 126]
    int B)
{
    __shared__ __align__(16) float w1s[200*WRS];     // 9600 B (w + bias packed)
    __shared__ __align__(16) float w2s[126*WRS];     // 6048 B (w + bias packed)
    __shared__ float w1rs[40], b1rs[16];
    __shared__ float tile[128*TRS];                  // 22016 B -> ~37.9 KB total

    const int tid  = threadIdx.x;
    const int base = blockIdx.x * 512;               // block covers 512 elements

    for (int i = tid; i < 2000; i += 256) w1s[(i/10)*WRS + i%10] = W1[i];
    for (int i = tid; i < 200;  i += 256) w1s[i*WRS + 10] = b1[i];
    for (int i = tid; i < 1260; i += 256) w2s[(i/10)*WRS + i%10] = W2[i];
    for (int i = tid; i < 126;  i += 256) w2s[i*WRS + 10] = b2[i];
    if (tid < 40)  w1rs[tid] = W1r[tid];
    if (tid < 10)  b1rs[tid] = b1r[tid];
    __syncthreads();

    const int eA = min(base + tid,       B - 1);
    const int eB = min(base + tid + 256, B - 1);
    const float4* __restrict__ qvA =
        reinterpret_cast<const float4*>(quat) + (size_t)eA * NJ;
    const float4* __restrict__ qvB =
        reinterpret_cast<const float4*>(quat) + (size_t)eB * NJ;

    // ---- chunk 0: joints 0..6 ----
    const float4 qA0 = qvA[0];
    const float4 qB0 = qvB[0];
#define H0ROW2(r) \
    const float hA0_##r = fmaxf( \
      fmaf(w1rs[(r)*4+3], qA0.w, fmaf(w1rs[(r)*4+2], qA0.z, \
      fmaf(w1rs[(r)*4+1], qA0.y, fmaf(w1rs[(r)*4+0], qA0.x, b1rs[r])))), 0.0f); \
    const float hB0_##r = fmaxf( \
      fmaf(w1rs[(r)*4+3], qB0.w, fmaf(w1rs[(r)*4+2], qB0.z, \
      fmaf(w1rs[(r)*4+1], qB0.y, fmaf(w1rs[(r)*4+0], qB0.x, b1rs[r])))), 0.0f);
    H0ROW2(0) H0ROW2(1) H0ROW2(2) H0ROW2(3) H0ROW2(4)
    H0ROW2(5) H0ROW2(6) H0ROW2(7) H0ROW2(8) H0ROW2(9)
#undef H0ROW2
    FROW2(0,0,0) FROW2(0,0,1) FROW2(0,0,2) FROW2(0,0,3) FROW2(0,0,4) FROW2(0,0,5)

    DO_JOINT(1,0,1)  DO_JOINT(2,0,2)  DO_JOINT(3,0,3)
    DO_JOINT(4,1,4)  DO_JOINT(5,2,5)  DO_JOINT(6,3,6)
    CHUNK_FLUSH(0, 0,1,2,3,4,5,6)

    // ---- chunk 1: joints 7..13 ----
    DO_JOINT(7,4,7)   DO_JOINT(8,5,8)   DO_JOINT(9,6,9)
    DO_JOINT(10,7,10) DO_JOINT(11,8,11)
    DO_JOINT(12,9,12) DO_JOINT(13,9,13)
    CHUNK_FLUSH(1, 7,8,9,10,11,12,13)

    // ---- chunk 2: joints 14..20 ----
    DO_JOINT(14,9,14)  DO_JOINT(15,12,15) DO_JOINT(16,13,16)
    DO_JOINT(17,14,17) DO_JOINT(18,16,18)
    DO_JOINT(19,17,19) DO_JOINT(20,18,20)
    CHUNK_FLUSH(2, 14,15,16,17,18,19,20)
}

extern "C" void kernel_launch(void* const* d_in, const int* in_sizes, int n_in,
                              void* d_out, int out_size, void* d_ws, size_t ws_size,
                              hipStream_t stream) {
    const float* quat = (const float*)d_in[0];
    const float* W1r  = (const float*)d_in[1];
    const float* b1r  = (const float*)d_in[2];
    const float* W1   = (const float*)d_in[3];
    const float* b1   = (const float*)d_in[4];
    const float* W2   = (const float*)d_in[5];
    const float* b2   = (const float*)d_in[6];
    float* out = (float*)d_out;

    const int B = in_sizes[0] / (NJ * 4);
    const int blocks = (B + 511) / 512;
    se_kernel<<<blocks, 256, 0, stream>>>(quat, W1r, b1r, W1, b1, W2, b2, out, B);
}

// Round 11
// 307.898 us; speedup vs baseline: 10.8467x; 10.8467x over previous
//
#include <hip/hip_runtime.h>

#define NJ  21
#define FT  6
#define WRS 12   // weight row stride: 10 w + bias@[10] + pad (48B, 16B-aligned)

// E=2 elements/thread, DIRECT stores, weights in LDS (bias packed in row).
// r6 cycle budget: LDS pipe ~70% busy (48 broadcast ds_read/joint/wave,
// 16 waves sharing one pipe) vs VALU 30% -> LDS-pipe bound. E=2 makes each
// weight ds_read feed two element chains (CSE) -> halves per-element demand.
// r8-r10 lesson: any flush structure holding both element sets' f-values
// across barriers spills catastrophically and VGPR pins at 64 under any
// occupancy annotation; r5 proved plain __launch_bounds__(256) lets VGPR
// float. So: no output tile, no flush -> f-values die at their store;
// LDS = weights only (15.5KB) -> occupancy capped by VGPR (~5 blocks/CU).

#define F10B(W, a0,a1,a2,a3,a4,a5,a6,a7,a8,a9) \
  fmaxf(fmaf((W)[9],(a9),fmaf((W)[8],(a8),fmaf((W)[7],(a7),fmaf((W)[6],(a6), \
        fmaf((W)[5],(a5),fmaf((W)[4],(a4),fmaf((W)[3],(a3),fmaf((W)[2],(a2), \
        fmaf((W)[1],(a1),fmaf((W)[0],(a0),(W)[10])))))))))), 0.0f)

#define HROW2(N,P,j,r) \
  const float hA##N##_##r = F10B(w1s + (((j)-1)*10 + (r))*WRS, \
      qA##N.x, qA##N.y, qA##N.z, qA##N.w, \
      fA##P##_0, fA##P##_1, fA##P##_2, fA##P##_3, fA##P##_4, fA##P##_5); \
  const float hB##N##_##r = F10B(w1s + (((j)-1)*10 + (r))*WRS, \
      qB##N.x, qB##N.y, qB##N.z, qB##N.w, \
      fB##P##_0, fB##P##_1, fB##P##_2, fB##P##_3, fB##P##_4, fB##P##_5);

#define FROW2(N,j,r) \
  const float fA##N##_##r = F10B(w2s + ((j)*6 + (r))*WRS, \
      hA##N##_0, hA##N##_1, hA##N##_2, hA##N##_3, hA##N##_4, \
      hA##N##_5, hA##N##_6, hA##N##_7, hA##N##_8, hA##N##_9); \
  const float fB##N##_##r = F10B(w2s + ((j)*6 + (r))*WRS, \
      hB##N##_0, hB##N##_1, hB##N##_2, hB##N##_3, hB##N##_4, \
      hB##N##_5, hB##N##_6, hB##N##_7, hB##N##_8, hB##N##_9);

// direct stores; f-values die here (no cross-barrier liveness)
#define STORE2(N,j) { \
  float2* oA_ = reinterpret_cast<float2*>(opA + (j)*FT); \
  oA_[0] = make_float2(fA##N##_0, fA##N##_1); \
  oA_[1] = make_float2(fA##N##_2, fA##N##_3); \
  oA_[2] = make_float2(fA##N##_4, fA##N##_5); \
  float2* oB_ = reinterpret_cast<float2*>(opB + (j)*FT); \
  oB_[0] = make_float2(fB##N##_0, fB##N##_1); \
  oB_[1] = make_float2(fB##N##_2, fB##N##_3); \
  oB_[2] = make_float2(fB##N##_4, fB##N##_5); }

#define DO_JOINT(j,P,N) \
  const float4 qA##N = qvA[j]; \
  const float4 qB##N = qvB[j]; \
  HROW2(N,P,j,0) HROW2(N,P,j,1) HROW2(N,P,j,2) HROW2(N,P,j,3) HROW2(N,P,j,4) \
  HROW2(N,P,j,5) HROW2(N,P,j,6) HROW2(N,P,j,7) HROW2(N,P,j,8) HROW2(N,P,j,9) \
  FROW2(N,j,0) FROW2(N,j,1) FROW2(N,j,2) FROW2(N,j,3) FROW2(N,j,4) FROW2(N,j,5) \
  STORE2(N,j)

__global__ __launch_bounds__(256) void se_kernel(
    const float* __restrict__ quat,   // [B, 21, 4]
    const float* __restrict__ W1r,    // [10, 4]
    const float* __restrict__ b1r,    // [10]
    const float* __restrict__ W1,     // [20, 10, 10]
    const float* __restrict__ b1,     // [20, 10]
    const float* __restrict__ W2,     // [21, 6, 10]
    const float* __restrict__ b2,     // [21, 6]
    float*       __restrict__ out,    // [B, 126]
    int B)
{
    __shared__ __align__(16) float w1s[200*WRS];   // 9600 B (w + bias packed)
    __shared__ __align__(16) float w2s[126*WRS];   // 6048 B (w + bias packed)
    __shared__ float w1rs[40], b1rs[16];           // total ~15.9 KB

    const int tid  = threadIdx.x;
    const int base = blockIdx.x * 512;             // block covers 512 elements

    for (int i = tid; i < 2000; i += 256) w1s[(i/10)*WRS + i%10] = W1[i];
    for (int i = tid; i < 200;  i += 256) w1s[i*WRS + 10] = b1[i];
    for (int i = tid; i < 1260; i += 256) w2s[(i/10)*WRS + i%10] = W2[i];
    for (int i = tid; i < 126;  i += 256) w2s[i*WRS + 10] = b2[i];
    if (tid < 40)  w1rs[tid] = W1r[tid];
    if (tid < 10)  b1rs[tid] = b1r[tid];
    __syncthreads();

    const int eA = min(base + tid,       B - 1);
    const int eB = min(base + tid + 256, B - 1);
    const float4* __restrict__ qvA =
        reinterpret_cast<const float4*>(quat) + (size_t)eA * NJ;
    const float4* __restrict__ qvB =
        reinterpret_cast<const float4*>(quat) + (size_t)eB * NJ;
    float* __restrict__ opA = out + (size_t)eA * (NJ * FT);
    float* __restrict__ opB = out + (size_t)eB * (NJ * FT);

    // ---- root (joint 0) ----
    const float4 qA0 = qvA[0];
    const float4 qB0 = qvB[0];
#define H0ROW2(r) \
    const float hA0_##r = fmaxf( \
      fmaf(w1rs[(r)*4+3], qA0.w, fmaf(w1rs[(r)*4+2], qA0.z, \
      fmaf(w1rs[(r)*4+1], qA0.y, fmaf(w1rs[(r)*4+0], qA0.x, b1rs[r])))), 0.0f); \
    const float hB0_##r = fmaxf( \
      fmaf(w1rs[(r)*4+3], qB0.w, fmaf(w1rs[(r)*4+2], qB0.z, \
      fmaf(w1rs[(r)*4+1], qB0.y, fmaf(w1rs[(r)*4+0], qB0.x, b1rs[r])))), 0.0f);
    H0ROW2(0) H0ROW2(1) H0ROW2(2) H0ROW2(3) H0ROW2(4)
    H0ROW2(5) H0ROW2(6) H0ROW2(7) H0ROW2(8) H0ROW2(9)
#undef H0ROW2
    FROW2(0,0,0) FROW2(0,0,1) FROW2(0,0,2) FROW2(0,0,3) FROW2(0,0,4) FROW2(0,0,5)
    STORE2(0,0)

    // ---- DFS over the kinematic tree (<=3 parent feature sets live) ----
    DO_JOINT(1,0,1)    DO_JOINT(4,1,4)    DO_JOINT(7,4,7)    DO_JOINT(10,7,10)
    DO_JOINT(2,0,2)    DO_JOINT(5,2,5)    DO_JOINT(8,5,8)    DO_JOINT(11,8,11)
    DO_JOINT(3,0,3)    DO_JOINT(6,3,6)    DO_JOINT(9,6,9)
    DO_JOINT(12,9,12)  DO_JOINT(15,12,15)
    DO_JOINT(13,9,13)  DO_JOINT(16,13,16) DO_JOINT(18,16,18) DO_JOINT(20,18,20)
    DO_JOINT(14,9,14)  DO_JOINT(17,14,17) DO_JOINT(19,17,19)
}

extern "C" void kernel_launch(void* const* d_in, const int* in_sizes, int n_in,
                              void* d_out, int out_size, void* d_ws, size_t ws_size,
                              hipStream_t stream) {
    const float* quat = (const float*)d_in[0];
    const float* W1r  = (const float*)d_in[1];
    const float* b1r  = (const float*)d_in[2];
    const float* W1   = (const float*)d_in[3];
    const float* b1   = (const float*)d_in[4];
    const float* W2   = (const float*)d_in[5];
    const float* b2   = (const float*)d_in[6];
    float* out = (float*)d_out;

    const int B = in_sizes[0] / (NJ * 4);
    const int blocks = (B + 511) / 512;
    se_kernel<<<blocks, 256, 0, stream>>>(quat, W1r, b1r, W1, b1, W2, b2, out, B);
}

// Round 12
// 187.338 us; speedup vs baseline: 17.8270x; 1.6435x over previous
//
#include <hip/hip_runtime.h>

#define NJ  21
#define FT  6
#define TRS 43   // output tile row stride (floats); odd -> bank-conflict-free
#define JW  176  // packed per-joint weights: 16 rows x (10w + bias) = 176

// r6's wall: ~48 broadcast ds_read_b128/joint/wave on the CU's ONE LDS pipe
// (16 waves sharing) ~= 161us of LDS serialization. Fix: per joint, stage
// weights into 3 lane-resident VGPRs (3x stride-1 ds_read_b32) and fetch each
// weight with v_readlane -> SGPR -> fma scalar operand. LDS 48->3 instr;
// +176 readlane rides the 4 parallel SIMDs instead of the single LDS pipe.
// VGPR cost: +3 over r6's proven no-spill layout (hard constraint: RA pins
// at ~64 and spills, r8-r11). E=1, r6 flush structure kept verbatim.

__device__ __forceinline__ float RL(float v, int l) {
    return __int_as_float(__builtin_amdgcn_readlane(__float_as_int(v), l));
}
// weight k of joint-block N (k compile-time constant -> single v_readlane)
#define RW(N,k) ((k) < 64 ? RL(wv##N##_0, (k)) : \
                 (k) < 128 ? RL(wv##N##_1, (k)-64) : RL(wv##N##_2, (k)-128))

// hidden row r (weights k = r*11 + 0..9, bias at r*11+10)
#define HROW(N,P,r) const float h##N##_##r = fmaxf( \
  fmaf(RW(N,(r)*11+9), f##P##_5, fmaf(RW(N,(r)*11+8), f##P##_4, \
  fmaf(RW(N,(r)*11+7), f##P##_3, fmaf(RW(N,(r)*11+6), f##P##_2, \
  fmaf(RW(N,(r)*11+5), f##P##_1, fmaf(RW(N,(r)*11+4), f##P##_0, \
  fmaf(RW(N,(r)*11+3), q##N.w,   fmaf(RW(N,(r)*11+2), q##N.z, \
  fmaf(RW(N,(r)*11+1), q##N.y,   fmaf(RW(N,(r)*11+0), q##N.x, \
  RW(N,(r)*11+10))))))))))), 0.0f);

// output row r (weights k = 110 + r*11 + 0..9, bias at +10)
#define FROW(N,r) const float f##N##_##r = fmaxf( \
  fmaf(RW(N,110+(r)*11+9), h##N##_9, fmaf(RW(N,110+(r)*11+8), h##N##_8, \
  fmaf(RW(N,110+(r)*11+7), h##N##_7, fmaf(RW(N,110+(r)*11+6), h##N##_6, \
  fmaf(RW(N,110+(r)*11+5), h##N##_5, fmaf(RW(N,110+(r)*11+4), h##N##_4, \
  fmaf(RW(N,110+(r)*11+3), h##N##_3, fmaf(RW(N,110+(r)*11+2), h##N##_2, \
  fmaf(RW(N,110+(r)*11+1), h##N##_1, fmaf(RW(N,110+(r)*11+0), h##N##_0, \
  RW(N,110+(r)*11+10))))))))))), 0.0f);

#define DO_JOINT(j,P,N) \
  const float4 q##N = qv[j]; \
  const float wv##N##_0 = jw[(j)*JW + lane]; \
  const float wv##N##_1 = jw[(j)*JW + 64 + lane]; \
  const float wv##N##_2 = jw[(j)*JW + 128 + lane]; \
  HROW(N,P,0) HROW(N,P,1) HROW(N,P,2) HROW(N,P,3) HROW(N,P,4) \
  HROW(N,P,5) HROW(N,P,6) HROW(N,P,7) HROW(N,P,8) HROW(N,P,9) \
  FROW(N,0) FROW(N,1) FROW(N,2) FROW(N,3) FROW(N,4) FROW(N,5)

#define PUT6(p, X) { (p)[0]=f##X##_0; (p)[1]=f##X##_1; (p)[2]=f##X##_2; \
                     (p)[3]=f##X##_3; (p)[4]=f##X##_4; (p)[5]=f##X##_5; }

#define HALF_FLUSH(k, half, N0,N1,N2,N3,N4,N5,N6) \
  __syncthreads(); \
  if ((tid >> 7) == (half)) { \
    float* tr_ = tile + (tid & 127) * TRS; \
    PUT6(tr_+0,  N0) PUT6(tr_+6,  N1) PUT6(tr_+12, N2) PUT6(tr_+18, N3) \
    PUT6(tr_+24, N4) PUT6(tr_+30, N5) PUT6(tr_+36, N6) \
  } \
  __syncthreads(); \
  { const int lane_ = tid & 63, w_ = tid >> 6; \
    _Pragma("unroll") \
    for (int i_ = 0; i_ < 21; ++i_) { \
      const int idx_ = w_ * 1344 + i_ * 64 + lane_; \
      const int row_ = idx_ / 42, col_ = idx_ - row_ * 42; \
      const int rg_  = base + (half)*128 + row_; \
      if (rg_ < B) out[(size_t)rg_ * 126 + (k)*42 + col_] = tile[row_ * TRS + col_]; \
    } \
  }

#define CHUNK_FLUSH(k, N0,N1,N2,N3,N4,N5,N6) \
  HALF_FLUSH(k, 0, N0,N1,N2,N3,N4,N5,N6) \
  HALF_FLUSH(k, 1, N0,N1,N2,N3,N4,N5,N6)

__global__ __launch_bounds__(256, 4) void se_kernel(
    const float* __restrict__ quat,   // [B, 21, 4]
    const float* __restrict__ W1r,    // [10, 4]
    const float* __restrict__ b1r,    // [10]
    const float* __restrict__ W1,     // [20, 10, 10]
    const float* __restrict__ b1,     // [20, 10]
    const float* __restrict__ W2,     // [21, 6, 10]
    const float* __restrict__ b2,     // [21, 6]
    float*       __restrict__ out,    // [B, 126]
    int B)
{
    __shared__ float jw[NJ * JW];     // 14784 B packed weights
    __shared__ float tile[128 * TRS]; // 22016 B -> total ~36 KB, 4 blocks/CU

    const int tid  = threadIdx.x;
    const int lane = tid & 63;
    const int base = blockIdx.x * 256;

    // ---- stage packed weights (joint j block: 110 W1|b1 then 66 W2|b2) ----
    for (int i = tid; i < 20*110; i += 256) {          // joints 1..20, layer 1
        const int j = i / 110, k = i % 110, r = k / 11, c = k % 11;
        jw[(j+1)*JW + k] = (c < 10) ? W1[j*100 + r*10 + c] : b1[j*10 + r];
    }
    for (int i = tid; i < 20*66; i += 256) {           // joints 1..20, layer 2
        const int j = i / 66, k = i % 66, r = k / 11, c = k % 11;
        jw[(j+1)*JW + 110 + k] = (c < 10) ? W2[(j+1)*60 + r*10 + c]
                                          : b2[(j+1)*6 + r];
    }
    if (tid < 50) {                                    // root layer 1: 5/row
        const int r = tid / 5, c = tid % 5;
        jw[tid] = (c < 4) ? W1r[r*4 + c] : b1r[r];
    }
    if (tid < 66) {                                    // root layer 2 at +50
        const int r = tid / 11, c = tid % 11;
        jw[50 + tid] = (c < 10) ? W2[r*10 + c] : b2[r];
    }
    __syncthreads();

    const int bcl = min(base + tid, B - 1);
    const float4* __restrict__ qv =
        reinterpret_cast<const float4*>(quat) + (size_t)bcl * NJ;

    // ---- chunk 0: joints 0..6 ----
    // root: W1r rows are 5 floats (4w+bias at r*5+4); W2 block at +50
    const float4 q0 = qv[0];
    const float wv0_0 = jw[lane];
    const float wv0_1 = jw[64 + lane];
    const float wv0_2 = jw[128 + lane];    // unused (root block = 116), DCE'd
#define H0ROW(r) const float h0_##r = fmaxf( \
    fmaf(RW(0,(r)*5+3), q0.w, fmaf(RW(0,(r)*5+2), q0.z, \
    fmaf(RW(0,(r)*5+1), q0.y, fmaf(RW(0,(r)*5+0), q0.x, RW(0,(r)*5+4))))), 0.0f);
    H0ROW(0) H0ROW(1) H0ROW(2) H0ROW(3) H0ROW(4)
    H0ROW(5) H0ROW(6) H0ROW(7) H0ROW(8) H0ROW(9)
#undef H0ROW
#define F0ROW(r) const float f0_##r = fmaxf( \
    fmaf(RW(0,50+(r)*11+9), h0_9, fmaf(RW(0,50+(r)*11+8), h0_8, \
    fmaf(RW(0,50+(r)*11+7), h0_7, fmaf(RW(0,50+(r)*11+6), h0_6, \
    fmaf(RW(0,50+(r)*11+5), h0_5, fmaf(RW(0,50+(r)*11+4), h0_4, \
    fmaf(RW(0,50+(r)*11+3), h0_3, fmaf(RW(0,50+(r)*11+2), h0_2, \
    fmaf(RW(0,50+(r)*11+1), h0_1, fmaf(RW(0,50+(r)*11+0), h0_0, \
    RW(0,50+(r)*11+10))))))))))), 0.0f);
    F0ROW(0) F0ROW(1) F0ROW(2) F0ROW(3) F0ROW(4) F0ROW(5)
#undef F0ROW

    DO_JOINT(1,0,1)  DO_JOINT(2,0,2)  DO_JOINT(3,0,3)
    DO_JOINT(4,1,4)  DO_JOINT(5,2,5)  DO_JOINT(6,3,6)
    CHUNK_FLUSH(0, 0,1,2,3,4,5,6)

    // ---- chunk 1: joints 7..13 ----
    DO_JOINT(7,4,7)   DO_JOINT(8,5,8)   DO_JOINT(9,6,9)
    DO_JOINT(10,7,10) DO_JOINT(11,8,11)
    DO_JOINT(12,9,12) DO_JOINT(13,9,13)
    CHUNK_FLUSH(1, 7,8,9,10,11,12,13)

    // ---- chunk 2: joints 14..20 ----
    DO_JOINT(14,9,14)  DO_JOINT(15,12,15) DO_JOINT(16,13,16)
    DO_JOINT(17,14,17) DO_JOINT(18,16,18)
    DO_JOINT(19,17,19) DO_JOINT(20,18,20)
    CHUNK_FLUSH(2, 14,15,16,17,18,19,20)
}

extern "C" void kernel_launch(void* const* d_in, const int* in_sizes, int n_in,
                              void* d_out, int out_size, void* d_ws, size_t ws_size,
                              hipStream_t stream) {
    const float* quat = (const float*)d_in[0];
    const float* W1r  = (const float*)d_in[1];
    const float* b1r  = (const float*)d_in[2];
    const float* W1   = (const float*)d_in[3];
    const float* b1   = (const float*)d_in[4];
    const float* W2   = (const float*)d_in[5];
    const float* b2   = (const float*)d_in[6];
    float* out = (float*)d_out;

    const int B = in_sizes[0] / (NJ * 4);
    const int blocks = (B + 255) / 256;
    se_kernel<<<blocks, 256, 0, stream>>>(quat, W1r, b1r, W1, b1, W2, b2, out, B);
}